// Round 8
// baseline (503.601 us; speedup 1.0000x reference)
//
#include <hip/hip_runtime.h>
#include <hip/hip_bf16.h>
#include <stdint.h>

#define SEQ 2048
#define HDIM 128
#define NHEADS 32
#define NKVH 4

typedef unsigned short u16;
typedef __bf16 bf16_t;
typedef bf16_t bf16x8 __attribute__((ext_vector_type(8)));
typedef float floatx4 __attribute__((ext_vector_type(4)));

__device__ __forceinline__ float bf2f(u16 u) {
  union { uint32_t i; float f; } v; v.i = ((uint32_t)u) << 16; return v.f;
}
__device__ __forceinline__ u16 f2bf(float f) {
  if (__builtin_isnan(f)) return 0;
  union { float f; uint32_t i; } v; v.f = f;
  uint32_t r = v.i + 0x7fffu + ((v.i >> 16) & 1u);
  return (u16)(r >> 16);
}
__device__ __forceinline__ float loadf_any(const void* p, size_t i, int isbf) {
  return isbf ? bf2f(((const u16*)p)[i]) : ((const float*)p)[i];
}

__device__ __forceinline__ void gload_lds16(const u16* g, u16* l) {
  __builtin_amdgcn_global_load_lds((__attribute__((address_space(1))) void*)g,
                                   (__attribute__((address_space(3))) void*)l,
                                   16, 0, 0);
}

__device__ __forceinline__ floatx4 mfma16(bf16x8 a, bf16x8 b, floatx4 c) {
  return __builtin_amdgcn_mfma_f32_16x16x32_bf16(a, b, c, 0, 0, 0);
}

// ---------------------------------------------------------------------------
// Block-local dtype detection (r5-proven heuristic). Returns 1 if bf16.
// All threads of the block participate; result broadcast to all.
// ---------------------------------------------------------------------------
__device__ __forceinline__ int detect_bf16_block(const u16* x, int n) {
  __shared__ int s_cnt[3];
  __shared__ int s_flag;
  const int tid = threadIdx.x;
  const int nthr = blockDim.x;
  if (tid == 0) { s_cnt[0] = 0; s_cnt[1] = 0; s_cnt[2] = 0; }
  __syncthreads();
  const int ns = n < 8192 ? n : 8192;
  int sane = 0, zeven = 0, zodd = 0;
  for (int i = tid; i < ns; i += nthr) {
    const u16 u = x[i];
    const int e = (u >> 7) & 0xff;
    if ((e >= 96 && e <= 159) || u == 0) sane++;
    if (u == 0) { if (i & 1) zodd++; else zeven++; }
  }
#pragma unroll
  for (int off = 32; off >= 1; off >>= 1) {
    sane += __shfl_xor(sane, off, 64);
    zeven += __shfl_xor(zeven, off, 64);
    zodd += __shfl_xor(zodd, off, 64);
  }
  if ((tid & 63) == 0) {
    atomicAdd(&s_cnt[0], sane);
    atomicAdd(&s_cnt[1], zeven);
    atomicAdd(&s_cnt[2], zodd);
  }
  __syncthreads();
  if (tid == 0) {
    const int even = (ns + 1) / 2, odd = ns / 2;
    const bool mostly = (s_cnt[0] * 10 >= ns * 9);
    const bool fpconst = (s_cnt[1] * 2 >= even) && (s_cnt[2] * 10 <= odd);
    s_flag = (mostly && !fpconst) ? 1 : 0;
  }
  __syncthreads();
  return s_flag;
}

// 64x64 transpose tile helper (256 threads): in (R x C) -> out (C x R) bf16.
__device__ __forceinline__ void transpose_tile(
    const void* in, u16* out, int R, int C, int bx, int by, int isbf) {
  __shared__ u16 tile[64][65];
  const int c0 = bx * 64, r0 = by * 64;
  const int t = threadIdx.x;
#pragma unroll
  for (int i = 0; i < 16; i++) {
    const int idx = i * 256 + t;
    const int r = idx >> 6, c = idx & 63;
    const size_t gi = (size_t)(r0 + r) * C + c0 + c;
    tile[r][c] = isbf ? ((const u16*)in)[gi] : f2bf(((const float*)in)[gi]);
  }
  __syncthreads();
#pragma unroll
  for (int i = 0; i < 16; i++) {
    const int idx = i * 256 + t;
    const int cc = idx >> 6, rr = idx & 63;
    out[(size_t)(c0 + cc) * R + r0 + rr] = tile[rr][cc];
  }
}

// ---------------------------------------------------------------------------
// prep1: fused input prep. 3714 blocks, 256 thr.
//  [0,1024)    hidden -> Hb (bf16), 4096 elems/block
//  [1024,3072) wq transpose -> wqkvT rows 0..4095
//  [3072,3328) wk transpose -> wqkvT rows 4096..4607
//  [3328,3584) wv transpose -> wqkvT rows 4608..5119
//  [3584,3648) cos -> cosf (fp32), 4096/block
//  [3648,3712) sin -> sinf
//  3712: qnw -> qnwf; 3713: knw -> knwf
// ---------------------------------------------------------------------------
struct PrepArgs {
  const void *hidden, *wq, *wk, *wv, *cosb, *sinb, *qnw, *knw;
  int n_hidden, n_wq, n_wk, n_wv, n_cs;
  u16 *Hb, *wqkvT;
  float *cosf, *sinf, *qnwf, *knwf;
};

__global__ __launch_bounds__(256) void prep1(PrepArgs a) {
  int b = blockIdx.x;
  if (b < 1024) {
    const int isbf = detect_bf16_block((const u16*)a.hidden, a.n_hidden);
    const int base = b * 4096;
    for (int i = threadIdx.x; i < 4096; i += 256)
      a.Hb[base + i] = isbf ? ((const u16*)a.hidden)[base + i]
                            : f2bf(((const float*)a.hidden)[base + i]);
    return;
  }
  b -= 1024;
  if (b < 2048) {
    const int isbf = detect_bf16_block((const u16*)a.wq, a.n_wq);
    transpose_tile(a.wq, a.wqkvT, 2048, 4096, b & 63, b >> 6, isbf);
    return;
  }
  b -= 2048;
  if (b < 256) {
    const int isbf = detect_bf16_block((const u16*)a.wk, a.n_wk);
    transpose_tile(a.wk, a.wqkvT + 4096ull * 2048, 2048, 512, b & 7, b >> 3, isbf);
    return;
  }
  b -= 256;
  if (b < 256) {
    const int isbf = detect_bf16_block((const u16*)a.wv, a.n_wv);
    transpose_tile(a.wv, a.wqkvT + 4608ull * 2048, 2048, 512, b & 7, b >> 3, isbf);
    return;
  }
  b -= 256;
  if (b < 64) {
    const int isbf = detect_bf16_block((const u16*)a.cosb, a.n_cs);
    const int base = b * 4096;
    for (int i = threadIdx.x; i < 4096; i += 256)
      a.cosf[base + i] = loadf_any(a.cosb, base + i, isbf);
    return;
  }
  b -= 64;
  if (b < 64) {
    const int isbf = detect_bf16_block((const u16*)a.sinb, a.n_cs);
    const int base = b * 4096;
    for (int i = threadIdx.x; i < 4096; i += 256)
      a.sinf[base + i] = loadf_any(a.sinb, base + i, isbf);
    return;
  }
  b -= 64;
  if (b == 0) {
    const int isbf = detect_bf16_block((const u16*)a.qnw, 128);
    for (int i = threadIdx.x; i < 128; i += 256)
      a.qnwf[i] = loadf_any(a.qnw, i, isbf);
    return;
  }
  const int isbf = detect_bf16_block((const u16*)a.knw, 128);
  for (int i = threadIdx.x; i < 128; i += 256)
    a.knwf[i] = loadf_any(a.knw, i, isbf);
}

// ---------------------------------------------------------------------------
// C(MxN) = A(MxK) @ BT(NxK)^T, bf16 in/out, fp32 acc. m97 structure + LDS
// XOR swizzle (s' = s ^ (row&3) ^ ((row>>2)&3)) -> 2-way banks (free).
// Optional gate: run only when detect(gate)==gate_want.
// ---------------------------------------------------------------------------
__global__ __launch_bounds__(256) void gemm_bt_bf16(
    const u16* __restrict__ A, const u16* __restrict__ BT,
    u16* __restrict__ C, int M, int N, int K,
    const u16* gate, int gate_n, int gate_want) {
  if (gate) {
    if (detect_bf16_block(gate, gate_n) != gate_want) return;
  }
  __shared__ alignas(16) u16 As[128 * 32];
  __shared__ alignas(16) u16 Bs[128 * 32];
  const int t = threadIdx.x;
  const int w = t >> 6;
  const int lane = t & 63;
  const int lhi = lane >> 4, llo = lane & 15;
  const int m0 = blockIdx.y * 128, n0 = blockIdx.x * 128;
  const int wm = (w & 1) * 64, wn = (w >> 1) * 64;
  const int fg = (llo & 3) ^ ((llo >> 2) & 3);  // frag-read swizzle

  floatx4 acc[4][4];
#pragma unroll
  for (int i = 0; i < 4; i++)
#pragma unroll
    for (int j = 0; j < 4; j++) acc[i][j] = (floatx4)(0.0f);

  for (int k0 = 0; k0 < K; k0 += 32) {
#pragma unroll
    for (int r = 0; r < 2; r++) {
      const int c = r * 256 + t;
      const int row = c >> 2, s = c & 3;
      const int g = (row & 3) ^ ((row >> 2) & 3);
      const int base = (r * 256 + w * 64) * 8;
      gload_lds16(A + (size_t)(m0 + row) * K + k0 + ((s ^ g) * 8), &As[base]);
      gload_lds16(BT + (size_t)(n0 + row) * K + k0 + ((s ^ g) * 8), &Bs[base]);
    }
    __syncthreads();
    bf16x8 af[4], bfr[4];
#pragma unroll
    for (int i = 0; i < 4; i++)
      af[i] = *(const bf16x8*)&As[(wm + i * 16 + llo) * 32 + ((lhi ^ fg) * 8)];
#pragma unroll
    for (int j = 0; j < 4; j++)
      bfr[j] = *(const bf16x8*)&Bs[(wn + j * 16 + llo) * 32 + ((lhi ^ fg) * 8)];
#pragma unroll
    for (int i = 0; i < 4; i++)
#pragma unroll
      for (int j = 0; j < 4; j++)
        acc[i][j] = mfma16(af[i], bfr[j], acc[i][j]);
    __syncthreads();
  }
#pragma unroll
  for (int i = 0; i < 4; i++) {
    const int row0 = m0 + wm + i * 16 + lhi * 4;
#pragma unroll
    for (int j = 0; j < 4; j++) {
      const int col = n0 + wn + j * 16 + llo;
#pragma unroll
      for (int r = 0; r < 4; r++)
        C[(size_t)(row0 + r) * N + col] = f2bf(acc[i][j][r]);
    }
  }
}

// ---------------------------------------------------------------------------
// Split-K GEMM, fp32 atomic epilogue into pre-zeroed C. Runs only when the
// output dtype (detected from gate=hidden) is fp32. grid (N/128, M/128, KS).
// ---------------------------------------------------------------------------
__global__ __launch_bounds__(256) void gemm_osplit(
    const u16* __restrict__ A, const u16* __restrict__ BT,
    float* __restrict__ C, int M, int N, int K, int KSLICE,
    const u16* gate, int gate_n) {
  if (detect_bf16_block(gate, gate_n) != 0) return;
  __shared__ alignas(16) u16 As[128 * 32];
  __shared__ alignas(16) u16 Bs[128 * 32];
  const int t = threadIdx.x;
  const int w = t >> 6;
  const int lane = t & 63;
  const int lhi = lane >> 4, llo = lane & 15;
  const int m0 = blockIdx.y * 128, n0 = blockIdx.x * 128;
  const int wm = (w & 1) * 64, wn = (w >> 1) * 64;
  const int fg = (llo & 3) ^ ((llo >> 2) & 3);
  const int kbase = blockIdx.z * KSLICE;

  floatx4 acc[4][4];
#pragma unroll
  for (int i = 0; i < 4; i++)
#pragma unroll
    for (int j = 0; j < 4; j++) acc[i][j] = (floatx4)(0.0f);

  for (int k0 = kbase; k0 < kbase + KSLICE; k0 += 32) {
#pragma unroll
    for (int r = 0; r < 2; r++) {
      const int c = r * 256 + t;
      const int row = c >> 2, s = c & 3;
      const int g = (row & 3) ^ ((row >> 2) & 3);
      const int base = (r * 256 + w * 64) * 8;
      gload_lds16(A + (size_t)(m0 + row) * K + k0 + ((s ^ g) * 8), &As[base]);
      gload_lds16(BT + (size_t)(n0 + row) * K + k0 + ((s ^ g) * 8), &Bs[base]);
    }
    __syncthreads();
    bf16x8 af[4], bfr[4];
#pragma unroll
    for (int i = 0; i < 4; i++)
      af[i] = *(const bf16x8*)&As[(wm + i * 16 + llo) * 32 + ((lhi ^ fg) * 8)];
#pragma unroll
    for (int j = 0; j < 4; j++)
      bfr[j] = *(const bf16x8*)&Bs[(wn + j * 16 + llo) * 32 + ((lhi ^ fg) * 8)];
#pragma unroll
    for (int i = 0; i < 4; i++)
#pragma unroll
      for (int j = 0; j < 4; j++)
        acc[i][j] = mfma16(af[i], bfr[j], acc[i][j]);
    __syncthreads();
  }
#pragma unroll
  for (int i = 0; i < 4; i++) {
    const int row0 = m0 + wm + i * 16 + lhi * 4;
#pragma unroll
    for (int j = 0; j < 4; j++) {
      const int col = n0 + wn + j * 16 + llo;
#pragma unroll
      for (int r = 0; r < 4; r++)
        unsafeAtomicAdd(&C[(size_t)(row0 + r) * N + col], acc[i][j][r]);
    }
  }
}

// ---------------------------------------------------------------------------
// RMSNorm + RoPE in place on QKV (S x 5120): Q cols 0..4095, K 4096..4607.
// Aux inputs pre-converted to fp32. grid (S, 36), block 128.
// ---------------------------------------------------------------------------
__global__ __launch_bounds__(128) void norm_rope(
    u16* __restrict__ QKV, const float* __restrict__ qw,
    const float* __restrict__ kw, const float* __restrict__ cosf,
    const float* __restrict__ sinf) {
  const int s = blockIdx.x, hy = blockIdx.y, d = threadIdx.x;
  const bool isQ = hy < NHEADS;
  const int col = isQ ? hy * HDIM : 4096 + (hy - NHEADS) * HDIM;
  u16* ptr = QKV + (size_t)s * 5120 + col + d;
  const float x = bf2f(*ptr);
  float v = x * x;
#pragma unroll
  for (int off = 32; off >= 1; off >>= 1) v += __shfl_xor(v, off, 64);
  __shared__ float sw[2];
  __shared__ float sh[128];
  if ((d & 63) == 0) sw[d >> 6] = v;
  __syncthreads();
  const float mean = (sw[0] + sw[1]) * (1.0f / 128.0f);
  const float rn = rsqrtf(mean + 1e-6f);
  const float wv = isQ ? qw[d] : kw[d];
  const float xn = x * rn * wv;
  sh[d] = xn;
  __syncthreads();
  const float other = sh[d ^ 64];
  const float cv = cosf[(size_t)s * HDIM + d];
  const float sv = sinf[(size_t)s * HDIM + d];
  const float o = xn * cv + (d < 64 ? -other : other) * sv;
  *ptr = f2bf(o);
}

// ---------------------------------------------------------------------------
// prep2a: v_transpose (256 blocks) + conditional zero of fp32 d_out (1024).
// ---------------------------------------------------------------------------
__global__ __launch_bounds__(256) void prep2a(
    const u16* __restrict__ QKV, u16* __restrict__ Vt,
    float* __restrict__ outz, const u16* gate, int gate_n) {
  int b = blockIdx.x;
  if (b < 256) {
    __shared__ u16 tile[64][65];
    const int s0 = (b & 31) * 64, d0 = ((b >> 5) & 1) * 64, hk = b >> 6;
    const int t = threadIdx.x;
#pragma unroll
    for (int i = 0; i < 16; i++) {
      const int idx = i * 256 + t;
      const int r = idx >> 6, c = idx & 63;
      tile[r][c] = QKV[(size_t)(s0 + r) * 5120 + 4608 + hk * HDIM + d0 + c];
    }
    __syncthreads();
#pragma unroll
    for (int i = 0; i < 16; i++) {
      const int idx = i * 256 + t;
      const int dd = idx >> 6, ss = idx & 63;
      Vt[((size_t)hk * HDIM + d0 + dd) * SEQ + s0 + ss] = tile[ss][dd];
    }
    return;
  }
  b -= 256;
  // zero d_out (fp32 path only)
  if (detect_bf16_block(gate, gate_n) != 0) return;
  const int base = b * 4096;
  for (int i = threadIdx.x; i < 4096; i += 256) outz[base + i] = 0.0f;
}

// wo transpose (runs after flash; writes woT overlaying QKVp).
__global__ __launch_bounds__(256) void wo_transpose(
    const void* __restrict__ wo, u16* __restrict__ woT, int n_wo) {
  const int isbf = detect_bf16_block((const u16*)wo, n_wo);
  transpose_tile(wo, woT, 4096, 2048, blockIdx.x & 31, blockIdx.x >> 5, isbf);
}

// ---------------------------------------------------------------------------
// Flash attention (r7-proven): causal GQA, heavy-first 1-D grid, static-max
// softmax, XOR-swizzled K/V LDS, wave-private P.
// ---------------------------------------------------------------------------
__global__ __launch_bounds__(256) void flash_attn(
    const u16* __restrict__ QKV, const u16* __restrict__ Vt,
    u16* __restrict__ O) {
  __shared__ alignas(16) u16 Klds[64 * 128];
  __shared__ alignas(16) u16 Vlds[128 * 64];
  __shared__ alignas(16) u16 Plds[4][32 * 72];
  const int t = threadIdx.x;
  const int w = t >> 6;
  const int lane = t & 63;
  const int lhi = lane >> 4, llo = lane & 15;
  const int b = blockIdx.x;
  const int qt = (SEQ / 128 - 1) - (b >> 5);
  const int h = b & 31, hk = h >> 3;
  const int q0 = qt * 128;
  const int qw0 = q0 + w * 32;
  const float scale = 0.08838834764831845f;
  const float SMAX = 16.0f;

  bf16x8 qf[2][4];
#pragma unroll
  for (int i = 0; i < 2; i++)
#pragma unroll
    for (int c = 0; c < 4; c++)
      qf[i][c] = *(const bf16x8*)(QKV + (size_t)(qw0 + i * 16 + llo) * 5120 +
                                  h * HDIM + c * 32 + lhi * 8);

  floatx4 oacc[2][8];
  float lacc[2][4];
#pragma unroll
  for (int i = 0; i < 2; i++) {
#pragma unroll
    for (int d = 0; d < 8; d++) oacc[i][d] = (floatx4)(0.0f);
#pragma unroll
    for (int r = 0; r < 4; r++) lacc[i][r] = 0.0f;
  }

  const int ntiles = 2 * qt + 2;
  for (int tt = 0; tt < ntiles; tt++) {
    const int kv0 = tt * 64;
#pragma unroll
    for (int r = 0; r < 4; r++) {
      const int c = r * 256 + t;
      const int base = (r * 256 + w * 64) * 8;
      gload_lds16(QKV + (size_t)(kv0 + (c >> 4)) * 5120 + 4096 + hk * HDIM +
                      (((c & 15) ^ ((c >> 4) & 7)) * 8),
                  &Klds[base]);
      gload_lds16(Vt + ((size_t)hk * HDIM + (c >> 3)) * SEQ + kv0 +
                      (((c & 7) ^ ((c >> 3) & 7)) * 8),
                  &Vlds[base]);
    }
    __syncthreads();

    floatx4 sacc[2][4];
#pragma unroll
    for (int i = 0; i < 2; i++)
#pragma unroll
      for (int j = 0; j < 4; j++) sacc[i][j] = (floatx4)(0.0f);
#pragma unroll
    for (int j = 0; j < 4; j++) {
#pragma unroll
      for (int c = 0; c < 4; c++) {
        bf16x8 kf = *(const bf16x8*)&Klds[(j * 16 + llo) * 128 +
                                          (((c * 4 + lhi) ^ (llo & 7)) * 8)];
        sacc[0][j] = mfma16(qf[0][c], kf, sacc[0][j]);
        sacc[1][j] = mfma16(qf[1][c], kf, sacc[1][j]);
      }
    }
    if (kv0 + 64 > q0) {
#pragma unroll
      for (int i = 0; i < 2; i++)
#pragma unroll
        for (int j = 0; j < 4; j++) {
          const int n = kv0 + j * 16 + llo;
#pragma unroll
          for (int r = 0; r < 4; r++) {
            const int mm = qw0 + i * 16 + lhi * 4 + r;
            if (n > mm) sacc[i][j][r] = -30000.0f;
          }
        }
    }
#pragma unroll
    for (int i = 0; i < 2; i++)
#pragma unroll
      for (int j = 0; j < 4; j++)
#pragma unroll
        for (int r = 0; r < 4; r++) {
          const float p = __expf(fmaf(sacc[i][j][r], scale, -SMAX));
          lacc[i][r] += p;
          Plds[w][(i * 16 + lhi * 4 + r) * 72 + j * 16 + llo] = f2bf(p);
        }
    asm volatile("" ::: "memory");
    __builtin_amdgcn_s_waitcnt(0);
    asm volatile("" ::: "memory");
#pragma unroll
    for (int c = 0; c < 2; c++) {
      bf16x8 pf0 = *(const bf16x8*)&Plds[w][llo * 72 + c * 32 + lhi * 8];
      bf16x8 pf1 = *(const bf16x8*)&Plds[w][(16 + llo) * 72 + c * 32 + lhi * 8];
#pragma unroll
      for (int d = 0; d < 8; d++) {
        bf16x8 vf = *(const bf16x8*)&Vlds[(d * 16 + llo) * 64 +
                                          (((c * 4 + lhi) ^ (llo & 7)) * 8)];
        oacc[0][d] = mfma16(pf0, vf, oacc[0][d]);
        oacc[1][d] = mfma16(pf1, vf, oacc[1][d]);
      }
    }
    __syncthreads();
  }
#pragma unroll
  for (int i = 0; i < 2; i++)
#pragma unroll
    for (int r = 0; r < 4; r++) {
#pragma unroll
      for (int off = 1; off < 16; off <<= 1)
        lacc[i][r] += __shfl_xor(lacc[i][r], off, 64);
      const float linv = 1.0f / lacc[i][r];
      const int row = qw0 + i * 16 + lhi * 4 + r;
#pragma unroll
      for (int d = 0; d < 8; d++)
        O[(size_t)row * 4096 + h * HDIM + d * 16 + llo] =
            f2bf(oacc[i][d][r] * linv);
    }
}

// ---------------------------------------------------------------------------
extern "C" void kernel_launch(void* const* d_in, const int* in_sizes, int n_in,
                              void* d_out, int out_size, void* d_ws, size_t ws_size,
                              hipStream_t stream) {
  char* ws = (char*)d_ws;
  u16* wqkvT = (u16*)(ws);                          // 20 MB (5120,2048)
  u16* QKVp  = (u16*)(ws + (20ull << 20));          // 20 MB (S,5120)
  u16* Vt    = (u16*)(ws + (40ull << 20));          //  2 MB (NKV,HD,S)
  float* cosf = (float*)(ws + (42ull << 20));       //  1 MB
  float* sinf = (float*)(ws + (43ull << 20));       //  1 MB
  float* qnwf = (float*)(ws + (44ull << 20));       //  512 B
  float* knwf = (float*)(ws + (44ull << 20) + 512); //  512 B
  u16* attnO = wqkvT;          // overlays wqkvT (dead after QKV GEMM)
  u16* woT   = QKVp;           // overlays QKVp (dead after flash)
  u16* Hb    = (u16*)d_out;    // bf16 hidden scratch (dead before O-proj)
  const u16* gate = (const u16*)d_in[0];
  const int gate_n = in_sizes[0];

  PrepArgs pa;
  pa.hidden = d_in[0]; pa.wq = d_in[1]; pa.wk = d_in[2]; pa.wv = d_in[3];
  pa.cosb = d_in[7]; pa.sinb = d_in[8]; pa.qnw = d_in[5]; pa.knw = d_in[6];
  pa.n_hidden = in_sizes[0]; pa.n_wq = in_sizes[1]; pa.n_wk = in_sizes[2];
  pa.n_wv = in_sizes[3]; pa.n_cs = in_sizes[7];
  pa.Hb = Hb; pa.wqkvT = wqkvT;
  pa.cosf = cosf; pa.sinf = sinf; pa.qnwf = qnwf; pa.knwf = knwf;

  prep1<<<3714, 256, 0, stream>>>(pa);

  // Fused QKV projection: (S,2048) @ (2048,5120)^T-form -> (S,5120) bf16
  gemm_bt_bf16<<<dim3(40, 16), 256, 0, stream>>>(
      Hb, wqkvT, QKVp, 2048, 5120, 2048, nullptr, 0, 0);

  norm_rope<<<dim3(2048, NHEADS + NKVH), 128, 0, stream>>>(
      QKVp, qnwf, knwf, cosf, sinf);

  // v_transpose + zero d_out (fp32 path); Hb dead, QKVp live (V cols only read)
  prep2a<<<1280, 256, 0, stream>>>(QKVp, Vt, (float*)d_out, gate, gate_n);

  flash_attn<<<512, 256, 0, stream>>>(QKVp, Vt, attnO);

  // woT overlays QKVp (dead after flash)
  wo_transpose<<<2048, 256, 0, stream>>>(d_in[4], woT, in_sizes[4]);

  // O-projection: split-K=4 atomics when out fp32; plain bf16 fallback else.
  gemm_osplit<<<dim3(16, 16, 4), 256, 0, stream>>>(
      attnO, woT, (float*)d_out, 2048, 2048, 4096, 1024, gate, gate_n);
  gemm_bt_bf16<<<dim3(16, 16), 256, 0, stream>>>(
      attnO, woT, (u16*)d_out, 2048, 2048, 4096, gate, gate_n, 1);
}